// Round 14
// baseline (185.350 us; speedup 1.0000x reference)
//
#include <hip/hip_runtime.h>
#include <hip/hip_bf16.h>
#include <math.h>

#define B_ 4
#define S_ 2048
#define D_ 512
#define H_ 8
#define DK_ 64

typedef __bf16 bf16x8 __attribute__((ext_vector_type(8)));
typedef float f32x16 __attribute__((ext_vector_type(16)));
typedef float f32x4 __attribute__((ext_vector_type(4)));

static __device__ __forceinline__ unsigned short f2bf(float f) {
    unsigned int u = __builtin_bit_cast(unsigned int, f);
    unsigned int r = (u + 0x7FFFu + ((u >> 16) & 1u)) >> 16;
    return (unsigned short)r;
}

// ---- W_Q/W_K [H][D][DK] f32 -> [H][DK][D] bf16 ----
__global__ void k_transpose_w(const float* __restrict__ wq, const float* __restrict__ wk,
                              unsigned short* __restrict__ wqT, unsigned short* __restrict__ wkT) {
    int idx = blockIdx.x * blockDim.x + threadIdx.x;
    const int n = H_ * DK_ * D_;
    const float* src = idx < n ? wq : wk;
    unsigned short* dst = idx < n ? wqT : wkT;
    int o = idx < n ? idx : idx - n;
    int d  = o % D_;
    int hk = o / D_;
    int k  = hk % DK_;
    int h  = hk / DK_;
    dst[o] = f2bf(src[(h * D_ + d) * DK_ + k]);
}

// ---- decay table tab[h][n] = gamma_h^n ----
__global__ void k_decay(float* __restrict__ tab) {
    int i = blockIdx.x * blockDim.x + threadIdx.x;
    if (i >= H_ * S_) return;
    int h = i / S_;
    int n = i % S_;
    double xv = -3.4657359027997265 - (double)h * (2.772588722239781 / 7.0);
    double g = 1.0 - exp(xv);
    tab[i] = (float)pow(g, (double)n);
}

// ---- merged zero-fill, 128-wide geometry ----
// grid (17, 32): x<16 -> panel-pair (p, 31-p) zero supertiles (uniform 15 x
// 64x128 per block); x==16 -> out0 chunk for this bh (524KB).
__global__ __launch_bounds__(256) void k_fill_all(float* __restrict__ aout, float* __restrict__ out0) {
    const int bh = blockIdx.y;
    const int tid = threadIdx.x;
    f32x4 z = {0.f, 0.f, 0.f, 0.f};
    if (blockIdx.x == 16) {
        f32x4* base = reinterpret_cast<f32x4*>(out0) + (size_t)bh * 32768;
#pragma unroll
        for (int j = 0; j < 128; ++j)
            base[tid + j * 256] = z;
        return;
    }
    float* ablk = aout + (size_t)bh * S_ * S_;
    const int p = blockIdx.x;
#pragma unroll
    for (int pp = 0; pp < 2; ++pp) {
        const int panel = pp ? (31 - p) : p;
        const int s0 = panel * 64;
        const int qq = panel >> 1;
        for (int st = qq + 1; st < 16; ++st) {
            float* base = ablk + (size_t)s0 * S_ + st * 128;
#pragma unroll
            for (int j = 0; j < 8; ++j) {
                int u = tid + j * 256;          // 0..2047 f32x4 slots in 64x128
                int row = u >> 5;
                int cq  = u & 31;
                *reinterpret_cast<f32x4*>(base + (size_t)row * S_ + cq * 4) = z;
            }
        }
    }
}

// ---- projection GEMM v2: A-tile in LDS, convert fused (unchanged) ----
__global__ __launch_bounds__(256, 2) void k_proj(const float* __restrict__ x,
                                                 const unsigned short* __restrict__ wqT,
                                                 const unsigned short* __restrict__ wkT,
                                                 unsigned short* __restrict__ qb,
                                                 unsigned short* __restrict__ kb) {
    const int tid  = threadIdx.x;
    const int lane = tid & 63;
    const int wave = tid >> 6;
    const int m0   = blockIdx.x * 32;
    const int half = blockIdx.y;
    const unsigned short* wt = half ? wkT : wqT;
    unsigned short* outp     = half ? kb  : qb;

    __shared__ unsigned short atile[32 * 520];

    {
        const float4* xsrc = reinterpret_cast<const float4*>(x + (size_t)m0 * D_);
#pragma unroll
        for (int i = 0; i < 16; ++i) {
            int u   = tid + i * 256;
            int row = u >> 7, c4 = u & 127;
            float4 v = xsrc[u];
            ushort4 o;
            o.x = f2bf(v.x); o.y = f2bf(v.y); o.z = f2bf(v.z); o.w = f2bf(v.w);
            *reinterpret_cast<ushort4*>(&atile[row * 520 + c4 * 4]) = o;
        }
    }
    __syncthreads();

    const int row  = lane & 31;
    const int col  = lane & 31;
    const int hi   = lane >> 5;
    const int koff = hi * 8;
    const int n0   = wave * 128;

    const unsigned short* b0 = wt + (size_t)(n0 +  0 + row) * D_ + koff;
    const unsigned short* b1 = wt + (size_t)(n0 + 32 + row) * D_ + koff;
    const unsigned short* b2 = wt + (size_t)(n0 + 64 + row) * D_ + koff;
    const unsigned short* b3 = wt + (size_t)(n0 + 96 + row) * D_ + koff;
    const unsigned short* ap = atile + row * 520 + koff;

    f32x16 acc0 = {}, acc1 = {}, acc2 = {}, acc3 = {};
#pragma unroll
    for (int kk = 0; kk < D_; kk += 16) {
        bf16x8 a = *reinterpret_cast<const bf16x8*>(ap + kk);
        acc0 = __builtin_amdgcn_mfma_f32_32x32x16_bf16(a, *reinterpret_cast<const bf16x8*>(b0 + kk), acc0, 0, 0, 0);
        acc1 = __builtin_amdgcn_mfma_f32_32x32x16_bf16(a, *reinterpret_cast<const bf16x8*>(b1 + kk), acc1, 0, 0, 0);
        acc2 = __builtin_amdgcn_mfma_f32_32x32x16_bf16(a, *reinterpret_cast<const bf16x8*>(b2 + kk), acc2, 0, 0, 0);
        acc3 = __builtin_amdgcn_mfma_f32_32x32x16_bf16(a, *reinterpret_cast<const bf16x8*>(b3 + kk), acc3, 0, 0, 0);
    }

#define EPI(ACC, NB) { \
    int n = n0 + (NB) * 32 + col; \
    int hh = n >> 6, k = n & 63; \
    _Pragma("unroll") \
    for (int r = 0; r < 16; ++r) { \
        int rowD = (r & 3) + 8 * (r >> 2) + 4 * hi; \
        int m = m0 + rowD; \
        int bidx = m >> 11, s = m & 2047; \
        outp[(((size_t)bidx * H_ + hh) * S_ + s) * DK_ + k] = f2bf(ACC[r]); \
    } }
    EPI(acc0, 0) EPI(acc1, 1) EPI(acc2, 2) EPI(acc3, 3)
#undef EPI
}

// ---- scores: 64x128 supertiles (32KB LDS) for 4-5 blocks/CU ----
// 512 blocks, XCD-aware id->(bh,p). Block: panels p,31-p -> 17 supertiles
// uniform. Wave w owns 64x32 col strip: full (factored decay) / diagonal
// (masked gather) / zero by geometry. Store: thread-linear f32x4 over the
// supertile (512B/wave segments).
__global__ __launch_bounds__(256) void k_score(const unsigned short* __restrict__ qb,
                                               const unsigned short* __restrict__ kb,
                                               const float* __restrict__ tab,
                                               float* __restrict__ aout) {
    const int tid  = threadIdx.x;
    const int lane = tid & 63;
    const int w    = tid >> 6;
    const int id   = blockIdx.x;
    const int c    = id & 7, sidx = id >> 3;
    const int bh   = (c >> 1) + 4 * (sidx >> 3);
    const int p    = ((sidx & 7) << 1) | (c & 1);
    const int h    = bh & (H_ - 1);
    float* ablk = aout + (size_t)bh * S_ * S_;
    const float* th = tab + h * S_;

    __shared__ float tile[64 * 128];            // 32KB

    const int col  = lane & 31;
    const int hi   = lane >> 5;
    const int koff = hi * 8;

    const float c1 = 1.0f / th[col];
    float grc[16];
    int rowDv[16];
#pragma unroll
    for (int r = 0; r < 16; ++r) {
        rowDv[r] = (r & 3) + 8 * (r >> 2) + 4 * hi;
        grc[r] = th[rowDv[r]] * c1;
    }

    for (int pp = 0; pp < 2; ++pp) {
        const int panel = pp ? (31 - p) : p;
        const int s0 = panel * 64;
        const int qq = panel >> 1;               // diagonal supertile (128-wide)

        bf16x8 qf[2][4];
#pragma unroll
        for (int rg = 0; rg < 2; ++rg) {
            const unsigned short* qp = qb + ((size_t)bh * S_ + s0 + rg * 32 + col) * DK_ + koff;
#pragma unroll
            for (int i = 0; i < 4; ++i)
                qf[rg][i] = *reinterpret_cast<const bf16x8*>(qp + 16 * i);
        }

        for (int st = 0; st <= qq; ++st) {
            const int t0  = st * 128;
            const int ct0 = t0 + w * 32;         // this wave's col strip
            if (ct0 <= s0 + 32) {                // strip intersects t<=s region
                f32x16 acc0 = {}, acc1 = {};
                const unsigned short* kp = kb + ((size_t)bh * S_ + ct0 + col) * DK_ + koff;
                bf16x8 kf0 = *reinterpret_cast<const bf16x8*>(kp);
                bf16x8 kf1 = *reinterpret_cast<const bf16x8*>(kp + 16);
                bf16x8 kf2 = *reinterpret_cast<const bf16x8*>(kp + 32);
                bf16x8 kf3 = *reinterpret_cast<const bf16x8*>(kp + 48);
                acc0 = __builtin_amdgcn_mfma_f32_32x32x16_bf16(qf[0][0], kf0, acc0, 0, 0, 0);
                acc0 = __builtin_amdgcn_mfma_f32_32x32x16_bf16(qf[0][1], kf1, acc0, 0, 0, 0);
                acc0 = __builtin_amdgcn_mfma_f32_32x32x16_bf16(qf[0][2], kf2, acc0, 0, 0, 0);
                acc0 = __builtin_amdgcn_mfma_f32_32x32x16_bf16(qf[0][3], kf3, acc0, 0, 0, 0);
                acc1 = __builtin_amdgcn_mfma_f32_32x32x16_bf16(qf[1][0], kf0, acc1, 0, 0, 0);
                acc1 = __builtin_amdgcn_mfma_f32_32x32x16_bf16(qf[1][1], kf1, acc1, 0, 0, 0);
                acc1 = __builtin_amdgcn_mfma_f32_32x32x16_bf16(qf[1][2], kf2, acc1, 0, 0, 0);
                acc1 = __builtin_amdgcn_mfma_f32_32x32x16_bf16(qf[1][3], kf3, acc1, 0, 0, 0);
                float* t0p = &tile[w * 32 + col];
                if (ct0 + 32 <= s0) {
                    // full strip: d >= 1 guaranteed -> factored decay
                    const float sc0 = th[s0 - ct0];
                    const float sc1 = th[s0 - ct0 + 32];
#pragma unroll
                    for (int r = 0; r < 16; ++r) {
                        t0p[rowDv[r] * 128]        = acc0[r] * grc[r] * sc0;
                        t0p[(32 + rowDv[r]) * 128] = acc1[r] * grc[r] * sc1;
                    }
                } else {
                    // diagonal strip: masked gather
                    const int db0 = s0 - ct0;
                    const int db1 = db0 + 32;
#pragma unroll
                    for (int r = 0; r < 16; ++r) {
                        int d0 = db0 + rowDv[r] - col;
                        int d1 = db1 + rowDv[r] - col;
                        t0p[rowDv[r] * 128]        = (d0 >= 0) ? acc0[r] * th[d0] : 0.0f;
                        t0p[(32 + rowDv[r]) * 128] = (d1 >= 0) ? acc1[r] * th[d1] : 0.0f;
                    }
                }
            } else {
                // zero strip
                f32x4 z = {0.f, 0.f, 0.f, 0.f};
#pragma unroll
                for (int k = 0; k < 8; ++k) {
                    int q = lane + k * 64;       // 0..511 quads in 64x32 strip
                    int row = q >> 3, cq = q & 7;
                    *reinterpret_cast<f32x4*>(&tile[row * 128 + w * 32 + cq * 4]) = z;
                }
            }
            __syncthreads();
            // store 64x128 supertile: 2048 f32x4 over 256 threads (8 each)
#pragma unroll
            for (int j = 0; j < 8; ++j) {
                int u = tid + j * 256;
                int row = u >> 5, cq = u & 31;
                f32x4 v = *reinterpret_cast<const f32x4*>(&tile[row * 128 + cq * 4]);
                *reinterpret_cast<f32x4*>(ablk + (size_t)(s0 + row) * S_ + t0 + cq * 4) = v;
            }
            __syncthreads();
        }
    }
}

extern "C" void kernel_launch(void* const* d_in, const int* in_sizes, int n_in,
                              void* d_out, int out_size, void* d_ws, size_t ws_size,
                              hipStream_t stream) {
    const float* x  = (const float*)d_in[0];
    const float* wq = (const float*)d_in[1];
    const float* wk = (const float*)d_in[2];

    char* ws = (char*)d_ws;
    unsigned short* wqT = (unsigned short*)(ws);               //    524,288 B
    unsigned short* wkT = (unsigned short*)(ws + 524288);      //    524,288 B
    unsigned short* qb  = (unsigned short*)(ws + 1048576);     //  8,388,608 B
    unsigned short* kb  = (unsigned short*)(ws + 9437184);     //  8,388,608 B
    float*          tab = (float*)(ws + 17825792);             //     65,536 B

    float* out0 = (float*)d_out;
    float* aout = (float*)d_out + (size_t)B_ * S_ * D_;

    hipLaunchKernelGGL(k_transpose_w, dim3((2*H_*DK_*D_ + 255)/256), dim3(256), 0, stream,
                       wq, wk, wqT, wkT);
    hipLaunchKernelGGL(k_decay, dim3((H_*S_ + 255)/256), dim3(256), 0, stream, tab);
    hipLaunchKernelGGL(k_fill_all, dim3(17, 32), dim3(256), 0, stream, aout, out0);
    hipLaunchKernelGGL(k_proj, dim3(B_*S_/32, 2), dim3(256), 0, stream,
                       x, wqT, wkT, qb, kb);
    hipLaunchKernelGGL(k_score, dim3(512), dim3(256), 0, stream,
                       qb, kb, tab, aout);
}

// Round 15
// 183.568 us; speedup vs baseline: 1.0097x; 1.0097x over previous
//
#include <hip/hip_runtime.h>
#include <hip/hip_bf16.h>
#include <math.h>

#define B_ 4
#define S_ 2048
#define D_ 512
#define H_ 8
#define DK_ 64

typedef __bf16 bf16x8 __attribute__((ext_vector_type(8)));
typedef float f32x16 __attribute__((ext_vector_type(16)));
typedef float f32x4 __attribute__((ext_vector_type(4)));

static __device__ __forceinline__ unsigned short f2bf(float f) {
    unsigned int u = __builtin_bit_cast(unsigned int, f);
    unsigned int r = (u + 0x7FFFu + ((u >> 16) & 1u)) >> 16;
    return (unsigned short)r;
}

// ---- W_Q/W_K [H][D][DK] f32 -> [H][DK][D] bf16 ----
__global__ void k_transpose_w(const float* __restrict__ wq, const float* __restrict__ wk,
                              unsigned short* __restrict__ wqT, unsigned short* __restrict__ wkT) {
    int idx = blockIdx.x * blockDim.x + threadIdx.x;
    const int n = H_ * DK_ * D_;
    const float* src = idx < n ? wq : wk;
    unsigned short* dst = idx < n ? wqT : wkT;
    int o = idx < n ? idx : idx - n;
    int d  = o % D_;
    int hk = o / D_;
    int k  = hk % DK_;
    int h  = hk / DK_;
    dst[o] = f2bf(src[(h * D_ + d) * DK_ + k]);
}

// ---- decay table tab[h][n] = gamma_h^n ----
__global__ void k_decay(float* __restrict__ tab) {
    int i = blockIdx.x * blockDim.x + threadIdx.x;
    if (i >= H_ * S_) return;
    int h = i / S_;
    int n = i % S_;
    double xv = -3.4657359027997265 - (double)h * (2.772588722239781 / 7.0);
    double g = 1.0 - exp(xv);
    tab[i] = (float)pow(g, (double)n);
}

// ---- merged zero-fill, 128-wide geometry ----
// grid (17, 32): x<16 -> panel-pair (p, 31-p) zero supertiles (uniform 15 x
// 64x128 per block); x==16 -> out0 chunk for this bh (524KB).
__global__ __launch_bounds__(256) void k_fill_all(float* __restrict__ aout, float* __restrict__ out0) {
    const int bh = blockIdx.y;
    const int tid = threadIdx.x;
    f32x4 z = {0.f, 0.f, 0.f, 0.f};
    if (blockIdx.x == 16) {
        f32x4* base = reinterpret_cast<f32x4*>(out0) + (size_t)bh * 32768;
#pragma unroll
        for (int j = 0; j < 128; ++j)
            base[tid + j * 256] = z;
        return;
    }
    float* ablk = aout + (size_t)bh * S_ * S_;
    const int p = blockIdx.x;
#pragma unroll
    for (int pp = 0; pp < 2; ++pp) {
        const int panel = pp ? (31 - p) : p;
        const int s0 = panel * 64;
        const int qq = panel >> 1;
        for (int st = qq + 1; st < 16; ++st) {
            float* base = ablk + (size_t)s0 * S_ + st * 128;
#pragma unroll
            for (int j = 0; j < 8; ++j) {
                int u = tid + j * 256;          // 0..2047 f32x4 slots in 64x128
                int row = u >> 5;
                int cq  = u & 31;
                *reinterpret_cast<f32x4*>(base + (size_t)row * S_ + cq * 4) = z;
            }
        }
    }
}

// ---- projection GEMM v2: A-tile in LDS, convert fused (unchanged) ----
__global__ __launch_bounds__(256, 2) void k_proj(const float* __restrict__ x,
                                                 const unsigned short* __restrict__ wqT,
                                                 const unsigned short* __restrict__ wkT,
                                                 unsigned short* __restrict__ qb,
                                                 unsigned short* __restrict__ kb) {
    const int tid  = threadIdx.x;
    const int lane = tid & 63;
    const int wave = tid >> 6;
    const int m0   = blockIdx.x * 32;
    const int half = blockIdx.y;
    const unsigned short* wt = half ? wkT : wqT;
    unsigned short* outp     = half ? kb  : qb;

    __shared__ unsigned short atile[32 * 520];

    {
        const float4* xsrc = reinterpret_cast<const float4*>(x + (size_t)m0 * D_);
#pragma unroll
        for (int i = 0; i < 16; ++i) {
            int u   = tid + i * 256;
            int row = u >> 7, c4 = u & 127;
            float4 v = xsrc[u];
            ushort4 o;
            o.x = f2bf(v.x); o.y = f2bf(v.y); o.z = f2bf(v.z); o.w = f2bf(v.w);
            *reinterpret_cast<ushort4*>(&atile[row * 520 + c4 * 4]) = o;
        }
    }
    __syncthreads();

    const int row  = lane & 31;
    const int col  = lane & 31;
    const int hi   = lane >> 5;
    const int koff = hi * 8;
    const int n0   = wave * 128;

    const unsigned short* b0 = wt + (size_t)(n0 +  0 + row) * D_ + koff;
    const unsigned short* b1 = wt + (size_t)(n0 + 32 + row) * D_ + koff;
    const unsigned short* b2 = wt + (size_t)(n0 + 64 + row) * D_ + koff;
    const unsigned short* b3 = wt + (size_t)(n0 + 96 + row) * D_ + koff;
    const unsigned short* ap = atile + row * 520 + koff;

    f32x16 acc0 = {}, acc1 = {}, acc2 = {}, acc3 = {};
#pragma unroll
    for (int kk = 0; kk < D_; kk += 16) {
        bf16x8 a = *reinterpret_cast<const bf16x8*>(ap + kk);
        acc0 = __builtin_amdgcn_mfma_f32_32x32x16_bf16(a, *reinterpret_cast<const bf16x8*>(b0 + kk), acc0, 0, 0, 0);
        acc1 = __builtin_amdgcn_mfma_f32_32x32x16_bf16(a, *reinterpret_cast<const bf16x8*>(b1 + kk), acc1, 0, 0, 0);
        acc2 = __builtin_amdgcn_mfma_f32_32x32x16_bf16(a, *reinterpret_cast<const bf16x8*>(b2 + kk), acc2, 0, 0, 0);
        acc3 = __builtin_amdgcn_mfma_f32_32x32x16_bf16(a, *reinterpret_cast<const bf16x8*>(b3 + kk), acc3, 0, 0, 0);
    }

#define EPI(ACC, NB) { \
    int n = n0 + (NB) * 32 + col; \
    int hh = n >> 6, k = n & 63; \
    _Pragma("unroll") \
    for (int r = 0; r < 16; ++r) { \
        int rowD = (r & 3) + 8 * (r >> 2) + 4 * hi; \
        int m = m0 + rowD; \
        int bidx = m >> 11, s = m & 2047; \
        outp[(((size_t)bidx * H_ + hh) * S_ + s) * DK_ + k] = f2bf(ACC[r]); \
    } }
    EPI(acc0, 0) EPI(acc1, 1) EPI(acc2, 2) EPI(acc3, 3)
#undef EPI
}

// ---- scores: 64x128 supertiles (32KB LDS) for 4-5 blocks/CU ----
// 512 blocks, XCD-aware id->(bh,p). Block: panels p,31-p -> 17 supertiles
// uniform. Wave w owns 64x32 col strip: full (factored decay) / diagonal
// (masked gather) / zero by geometry. Store: thread-linear f32x4 over the
// supertile (512B/wave segments).
__global__ __launch_bounds__(256) void k_score(const unsigned short* __restrict__ qb,
                                               const unsigned short* __restrict__ kb,
                                               const float* __restrict__ tab,
                                               float* __restrict__ aout) {
    const int tid  = threadIdx.x;
    const int lane = tid & 63;
    const int w    = tid >> 6;
    const int id   = blockIdx.x;
    const int c    = id & 7, sidx = id >> 3;
    const int bh   = (c >> 1) + 4 * (sidx >> 3);
    const int p    = ((sidx & 7) << 1) | (c & 1);
    const int h    = bh & (H_ - 1);
    float* ablk = aout + (size_t)bh * S_ * S_;
    const float* th = tab + h * S_;

    __shared__ float tile[64 * 128];            // 32KB

    const int col  = lane & 31;
    const int hi   = lane >> 5;
    const int koff = hi * 8;

    const float c1 = 1.0f / th[col];
    float grc[16];
    int rowDv[16];
#pragma unroll
    for (int r = 0; r < 16; ++r) {
        rowDv[r] = (r & 3) + 8 * (r >> 2) + 4 * hi;
        grc[r] = th[rowDv[r]] * c1;
    }

    for (int pp = 0; pp < 2; ++pp) {
        const int panel = pp ? (31 - p) : p;
        const int s0 = panel * 64;
        const int qq = panel >> 1;               // diagonal supertile (128-wide)

        bf16x8 qf[2][4];
#pragma unroll
        for (int rg = 0; rg < 2; ++rg) {
            const unsigned short* qp = qb + ((size_t)bh * S_ + s0 + rg * 32 + col) * DK_ + koff;
#pragma unroll
            for (int i = 0; i < 4; ++i)
                qf[rg][i] = *reinterpret_cast<const bf16x8*>(qp + 16 * i);
        }

        for (int st = 0; st <= qq; ++st) {
            const int t0  = st * 128;
            const int ct0 = t0 + w * 32;         // this wave's col strip
            if (ct0 <= s0 + 32) {                // strip intersects t<=s region
                f32x16 acc0 = {}, acc1 = {};
                const unsigned short* kp = kb + ((size_t)bh * S_ + ct0 + col) * DK_ + koff;
                bf16x8 kf0 = *reinterpret_cast<const bf16x8*>(kp);
                bf16x8 kf1 = *reinterpret_cast<const bf16x8*>(kp + 16);
                bf16x8 kf2 = *reinterpret_cast<const bf16x8*>(kp + 32);
                bf16x8 kf3 = *reinterpret_cast<const bf16x8*>(kp + 48);
                acc0 = __builtin_amdgcn_mfma_f32_32x32x16_bf16(qf[0][0], kf0, acc0, 0, 0, 0);
                acc0 = __builtin_amdgcn_mfma_f32_32x32x16_bf16(qf[0][1], kf1, acc0, 0, 0, 0);
                acc0 = __builtin_amdgcn_mfma_f32_32x32x16_bf16(qf[0][2], kf2, acc0, 0, 0, 0);
                acc0 = __builtin_amdgcn_mfma_f32_32x32x16_bf16(qf[0][3], kf3, acc0, 0, 0, 0);
                acc1 = __builtin_amdgcn_mfma_f32_32x32x16_bf16(qf[1][0], kf0, acc1, 0, 0, 0);
                acc1 = __builtin_amdgcn_mfma_f32_32x32x16_bf16(qf[1][1], kf1, acc1, 0, 0, 0);
                acc1 = __builtin_amdgcn_mfma_f32_32x32x16_bf16(qf[1][2], kf2, acc1, 0, 0, 0);
                acc1 = __builtin_amdgcn_mfma_f32_32x32x16_bf16(qf[1][3], kf3, acc1, 0, 0, 0);
                float* t0p = &tile[w * 32 + col];
                if (ct0 + 32 <= s0) {
                    // full strip: d >= 1 guaranteed -> factored decay
                    const float sc0 = th[s0 - ct0];
                    const float sc1 = th[s0 - ct0 + 32];
#pragma unroll
                    for (int r = 0; r < 16; ++r) {
                        t0p[rowDv[r] * 128]        = acc0[r] * grc[r] * sc0;
                        t0p[(32 + rowDv[r]) * 128] = acc1[r] * grc[r] * sc1;
                    }
                } else {
                    // diagonal strip: masked gather
                    const int db0 = s0 - ct0;
                    const int db1 = db0 + 32;
#pragma unroll
                    for (int r = 0; r < 16; ++r) {
                        int d0 = db0 + rowDv[r] - col;
                        int d1 = db1 + rowDv[r] - col;
                        t0p[rowDv[r] * 128]        = (d0 >= 0) ? acc0[r] * th[d0] : 0.0f;
                        t0p[(32 + rowDv[r]) * 128] = (d1 >= 0) ? acc1[r] * th[d1] : 0.0f;
                    }
                }
            } else {
                // zero strip
                f32x4 z = {0.f, 0.f, 0.f, 0.f};
#pragma unroll
                for (int k = 0; k < 8; ++k) {
                    int q = lane + k * 64;       // 0..511 quads in 64x32 strip
                    int row = q >> 3, cq = q & 7;
                    *reinterpret_cast<f32x4*>(&tile[row * 128 + w * 32 + cq * 4]) = z;
                }
            }
            __syncthreads();
            // store 64x128 supertile: 2048 f32x4 over 256 threads (8 each)
#pragma unroll
            for (int j = 0; j < 8; ++j) {
                int u = tid + j * 256;
                int row = u >> 5, cq = u & 31;
                f32x4 v = *reinterpret_cast<const f32x4*>(&tile[row * 128 + cq * 4]);
                *reinterpret_cast<f32x4*>(ablk + (size_t)(s0 + row) * S_ + t0 + cq * 4) = v;
            }
            __syncthreads();
        }
    }
}

extern "C" void kernel_launch(void* const* d_in, const int* in_sizes, int n_in,
                              void* d_out, int out_size, void* d_ws, size_t ws_size,
                              hipStream_t stream) {
    const float* x  = (const float*)d_in[0];
    const float* wq = (const float*)d_in[1];
    const float* wk = (const float*)d_in[2];

    char* ws = (char*)d_ws;
    unsigned short* wqT = (unsigned short*)(ws);               //    524,288 B
    unsigned short* wkT = (unsigned short*)(ws + 524288);      //    524,288 B
    unsigned short* qb  = (unsigned short*)(ws + 1048576);     //  8,388,608 B
    unsigned short* kb  = (unsigned short*)(ws + 9437184);     //  8,388,608 B
    float*          tab = (float*)(ws + 17825792);             //     65,536 B

    float* out0 = (float*)d_out;
    float* aout = (float*)d_out + (size_t)B_ * S_ * D_;

    hipLaunchKernelGGL(k_transpose_w, dim3((2*H_*DK_*D_ + 255)/256), dim3(256), 0, stream,
                       wq, wk, wqT, wkT);
    hipLaunchKernelGGL(k_decay, dim3((H_*S_ + 255)/256), dim3(256), 0, stream, tab);
    hipLaunchKernelGGL(k_fill_all, dim3(17, 32), dim3(256), 0, stream, aout, out0);
    hipLaunchKernelGGL(k_proj, dim3(B_*S_/32, 2), dim3(256), 0, stream,
                       x, wqT, wkT, qb, kb);
    hipLaunchKernelGGL(k_score, dim3(512), dim3(256), 0, stream,
                       qb, kb, tab, aout);
}

// Round 16
// 182.209 us; speedup vs baseline: 1.0172x; 1.0075x over previous
//
#include <hip/hip_runtime.h>
#include <hip/hip_bf16.h>
#include <math.h>

#define B_ 4
#define S_ 2048
#define D_ 512
#define H_ 8
#define DK_ 64

typedef __bf16 bf16x8 __attribute__((ext_vector_type(8)));
typedef float f32x16 __attribute__((ext_vector_type(16)));
typedef float f32x4 __attribute__((ext_vector_type(4)));

static __device__ __forceinline__ unsigned short f2bf(float f) {
    unsigned int u = __builtin_bit_cast(unsigned int, f);
    unsigned int r = (u + 0x7FFFu + ((u >> 16) & 1u)) >> 16;
    return (unsigned short)r;
}

// ---- W_Q/W_K [H][D][DK] f32 -> [H][DK][D] bf16 ----
__global__ void k_transpose_w(const float* __restrict__ wq, const float* __restrict__ wk,
                              unsigned short* __restrict__ wqT, unsigned short* __restrict__ wkT) {
    int idx = blockIdx.x * blockDim.x + threadIdx.x;
    const int n = H_ * DK_ * D_;
    const float* src = idx < n ? wq : wk;
    unsigned short* dst = idx < n ? wqT : wkT;
    int o = idx < n ? idx : idx - n;
    int d  = o % D_;
    int hk = o / D_;
    int k  = hk % DK_;
    int h  = hk / DK_;
    dst[o] = f2bf(src[(h * D_ + d) * DK_ + k]);
}

// ---- decay table tab[h][n] = gamma_h^n ----
__global__ void k_decay(float* __restrict__ tab) {
    int i = blockIdx.x * blockDim.x + threadIdx.x;
    if (i >= H_ * S_) return;
    int h = i / S_;
    int n = i % S_;
    double xv = -3.4657359027997265 - (double)h * (2.772588722239781 / 7.0);
    double g = 1.0 - exp(xv);
    tab[i] = (float)pow(g, (double)n);
}

// ---- merged zero-fill: out0 (16.8MB) + strictly-upper supertiles of A (224MB) ----
// (identical to round 12)
__global__ __launch_bounds__(256) void k_fill_all(float* __restrict__ aout, float* __restrict__ out0) {
    const int bh = blockIdx.y;
    f32x4 z = {0.f, 0.f, 0.f, 0.f};
    if (blockIdx.x >= 112) {
        const int chunk = (blockIdx.x - 112) + 4 * bh;
        f32x4* base = reinterpret_cast<f32x4*>(out0) + (size_t)chunk * 8192;
#pragma unroll
        for (int j = 0; j < 32; ++j)
            base[threadIdx.x + j * 256] = z;
        return;
    }
    int r = blockIdx.x;
    int g = 0, cum = 0;
    for (; g < 7; ++g) { int cnt = 4 * (7 - g); if (r < cum + cnt) break; cum += cnt; }
    const int rr  = r - cum;
    const int per = 7 - g;
    const int panel = g * 4 + rr / per;
    const int st    = g + 1 + rr % per;

    float* base = aout + (size_t)bh * S_ * S_ + (size_t)(panel * 64) * S_ + st * 256;
    const int t = threadIdx.x;
#pragma unroll
    for (int j = 0; j < 16; ++j) {
        int u = t + j * 256;
        int row = u >> 6;
        int c4  = u & 63;
        *reinterpret_cast<f32x4*>(base + (size_t)row * S_ + c4 * 4) = z;
    }
}

// ---- projection GEMM v2: A-tile in LDS, convert fused (identical to round 12) ----
__global__ __launch_bounds__(256, 2) void k_proj(const float* __restrict__ x,
                                                 const unsigned short* __restrict__ wqT,
                                                 const unsigned short* __restrict__ wkT,
                                                 unsigned short* __restrict__ qb,
                                                 unsigned short* __restrict__ kb) {
    const int tid  = threadIdx.x;
    const int lane = tid & 63;
    const int wave = tid >> 6;
    const int m0   = blockIdx.x * 32;
    const int half = blockIdx.y;
    const unsigned short* wt = half ? wkT : wqT;
    unsigned short* outp     = half ? kb  : qb;

    __shared__ unsigned short atile[32 * 520];

    {
        const float4* xsrc = reinterpret_cast<const float4*>(x + (size_t)m0 * D_);
#pragma unroll
        for (int i = 0; i < 16; ++i) {
            int u   = tid + i * 256;
            int row = u >> 7, c4 = u & 127;
            float4 v = xsrc[u];
            ushort4 o;
            o.x = f2bf(v.x); o.y = f2bf(v.y); o.z = f2bf(v.z); o.w = f2bf(v.w);
            *reinterpret_cast<ushort4*>(&atile[row * 520 + c4 * 4]) = o;
        }
    }
    __syncthreads();

    const int row  = lane & 31;
    const int col  = lane & 31;
    const int hi   = lane >> 5;
    const int koff = hi * 8;
    const int n0   = wave * 128;

    const unsigned short* b0 = wt + (size_t)(n0 +  0 + row) * D_ + koff;
    const unsigned short* b1 = wt + (size_t)(n0 + 32 + row) * D_ + koff;
    const unsigned short* b2 = wt + (size_t)(n0 + 64 + row) * D_ + koff;
    const unsigned short* b3 = wt + (size_t)(n0 + 96 + row) * D_ + koff;
    const unsigned short* ap = atile + row * 520 + koff;

    f32x16 acc0 = {}, acc1 = {}, acc2 = {}, acc3 = {};
#pragma unroll
    for (int kk = 0; kk < D_; kk += 16) {
        bf16x8 a = *reinterpret_cast<const bf16x8*>(ap + kk);
        acc0 = __builtin_amdgcn_mfma_f32_32x32x16_bf16(a, *reinterpret_cast<const bf16x8*>(b0 + kk), acc0, 0, 0, 0);
        acc1 = __builtin_amdgcn_mfma_f32_32x32x16_bf16(a, *reinterpret_cast<const bf16x8*>(b1 + kk), acc1, 0, 0, 0);
        acc2 = __builtin_amdgcn_mfma_f32_32x32x16_bf16(a, *reinterpret_cast<const bf16x8*>(b2 + kk), acc2, 0, 0, 0);
        acc3 = __builtin_amdgcn_mfma_f32_32x32x16_bf16(a, *reinterpret_cast<const bf16x8*>(b3 + kk), acc3, 0, 0, 0);
    }

#define EPI(ACC, NB) { \
    int n = n0 + (NB) * 32 + col; \
    int hh = n >> 6, k = n & 63; \
    _Pragma("unroll") \
    for (int r = 0; r < 16; ++r) { \
        int rowD = (r & 3) + 8 * (r >> 2) + 4 * hi; \
        int m = m0 + rowD; \
        int bidx = m >> 11, s = m & 2047; \
        outp[(((size_t)bidx * H_ + hh) * S_ + s) * DK_ + k] = f2bf(ACC[r]); \
    } }
    EPI(acc0, 0) EPI(acc1, 1) EPI(acc2, 2) EPI(acc3, 3)
#undef EPI
}

// ---- scores: R12 geometry + raw lgkmcnt-only barriers + K prefetch ----
// Key change: the two __syncthreads (which emit s_waitcnt vmcnt(0) and drain
// all outstanding A-stores every supertile) are replaced by
// s_waitcnt lgkmcnt(0) + s_barrier — LDS hazards only need lgkmcnt; the
// global stores never need to drain inside the loop. K for supertile st+1 is
// prefetched into registers before st's epilogue, so its latency hides under
// a full supertile of work (consumption uses compiler-counted vmcnt).
__global__ __launch_bounds__(256) void k_score(const unsigned short* __restrict__ qb,
                                               const unsigned short* __restrict__ kb,
                                               const float* __restrict__ tab,
                                               float* __restrict__ aout) {
    const int lane = threadIdx.x & 63;
    const int w    = threadIdx.x >> 6;
    const int id   = blockIdx.x;
    const int c    = id & 7, sidx = id >> 3;
    const int bh   = (c >> 1) + 4 * (sidx >> 3);
    const int p    = ((sidx & 7) << 1) | (c & 1);
    const int h    = bh & (H_ - 1);
    float* ablk = aout + (size_t)bh * S_ * S_;
    const float* th = tab + h * S_;

    __shared__ float tile[64 * 256];            // 64KB

    const int col  = lane & 31;
    const int hi   = lane >> 5;
    const int koff = hi * 8;

    const float c1 = 1.0f / th[col];
    float grc[16];
    int rowDv[16];
#pragma unroll
    for (int r = 0; r < 16; ++r) {
        rowDv[r] = (r & 3) + 8 * (r >> 2) + 4 * hi;
        grc[r] = th[rowDv[r]] * c1;
    }

#define KLOAD(DST, ST) do { \
    _Pragma("unroll") \
    for (int cg_ = 0; cg_ < 2; ++cg_) { \
        const unsigned short* kp_ = kb + ((size_t)bh * S_ + (ST) * 256 + w * 64 + cg_ * 32 + col) * DK_ + koff; \
        DST[cg_][0] = *reinterpret_cast<const bf16x8*>(kp_); \
        DST[cg_][1] = *reinterpret_cast<const bf16x8*>(kp_ + 16); \
        DST[cg_][2] = *reinterpret_cast<const bf16x8*>(kp_ + 32); \
        DST[cg_][3] = *reinterpret_cast<const bf16x8*>(kp_ + 48); \
    } \
} while (0)

    for (int pp = 0; pp < 2; ++pp) {
        const int panel = pp ? (31 - p) : p;
        const int s0 = panel * 64;
        const int qq = panel >> 2;               // diagonal supertile index
        const int rb = panel & 3;                // diagonal wave within it

        bf16x8 qf[2][4];
#pragma unroll
        for (int rg = 0; rg < 2; ++rg) {
            const unsigned short* qp = qb + ((size_t)bh * S_ + s0 + rg * 32 + col) * DK_ + koff;
#pragma unroll
            for (int i = 0; i < 4; ++i)
                qf[rg][i] = *reinterpret_cast<const bf16x8*>(qp + 16 * i);
        }

        bf16x8 kc[2][4], kn[2][4];
        KLOAD(kc, 0);

        for (int st = 0; st <= qq; ++st) {
            const int t0  = st * 256;
            const int ct0 = t0 + w * 64;
            // prefetch next supertile's K (issued before epilogue/barriers;
            // consumed next iteration via counted vmcnt)
            if (st < qq) KLOAD(kn, st + 1);

            const bool active = (st < qq) || (w <= rb);
            if (active) {
                f32x16 acc[2][2] = {{{}, {}}, {{}, {}}};
#pragma unroll
                for (int cg = 0; cg < 2; ++cg) {
#pragma unroll
                    for (int rg = 0; rg < 2; ++rg) {
                        acc[rg][cg] = __builtin_amdgcn_mfma_f32_32x32x16_bf16(qf[rg][0], kc[cg][0], acc[rg][cg], 0, 0, 0);
                        acc[rg][cg] = __builtin_amdgcn_mfma_f32_32x32x16_bf16(qf[rg][1], kc[cg][1], acc[rg][cg], 0, 0, 0);
                        acc[rg][cg] = __builtin_amdgcn_mfma_f32_32x32x16_bf16(qf[rg][2], kc[cg][2], acc[rg][cg], 0, 0, 0);
                        acc[rg][cg] = __builtin_amdgcn_mfma_f32_32x32x16_bf16(qf[rg][3], kc[cg][3], acc[rg][cg], 0, 0, 0);
                    }
                }
                if (st < qq || w < rb) {
#pragma unroll
                    for (int rg = 0; rg < 2; ++rg) {
#pragma unroll
                        for (int cg = 0; cg < 2; ++cg) {
                            const float sc = th[s0 + rg * 32 - ct0 - cg * 32];
#pragma unroll
                            for (int r = 0; r < 16; ++r)
                                tile[(rg * 32 + rowDv[r]) * 256 + w * 64 + cg * 32 + col] =
                                    acc[rg][cg][r] * grc[r] * sc;
                        }
                    }
                } else {
                    // diagonal wave: masked gather path
#pragma unroll
                    for (int rg = 0; rg < 2; ++rg) {
#pragma unroll
                        for (int cg = 0; cg < 2; ++cg) {
                            const int dbase = 32 * (rg - cg);
#pragma unroll
                            for (int r = 0; r < 16; ++r) {
                                int d = dbase + rowDv[r] - col;
                                float v = (d >= 0) ? acc[rg][cg][r] * th[d] : 0.0f;
                                tile[(rg * 32 + rowDv[r]) * 256 + w * 64 + cg * 32 + col] = v;
                            }
                        }
                    }
                }
            } else {
                f32x4 z = {0.f, 0.f, 0.f, 0.f};
#pragma unroll
                for (int i = 0; i < 16; ++i) {
                    int r = i * 4 + (lane >> 4);
                    int cc = (lane & 15) * 4;
                    *reinterpret_cast<f32x4*>(&tile[r * 256 + w * 64 + cc]) = z;
                }
            }
            // barrier A: LDS writes visible (lgkmcnt only — do NOT drain stores)
            asm volatile("s_waitcnt lgkmcnt(0)" ::: "memory");
            __builtin_amdgcn_sched_barrier(0);
            __builtin_amdgcn_s_barrier();
            // store phase: one instr = one full 1KB row-chunk
#pragma unroll
            for (int r = 0; r < 16; ++r) {
                int row = w * 16 + r;
                f32x4 v = *reinterpret_cast<const f32x4*>(&tile[row * 256 + lane * 4]);
                *reinterpret_cast<f32x4*>(ablk + (size_t)(s0 + row) * S_ + t0 + lane * 4) = v;
            }
            // barrier B: ds_reads of tile complete before next epilogue overwrites
            asm volatile("s_waitcnt lgkmcnt(0)" ::: "memory");
            __builtin_amdgcn_sched_barrier(0);
            __builtin_amdgcn_s_barrier();
            // rotate prefetched K into current
#pragma unroll
            for (int cg = 0; cg < 2; ++cg)
#pragma unroll
                for (int i = 0; i < 4; ++i)
                    kc[cg][i] = kn[cg][i];
        }
    }
#undef KLOAD
}

extern "C" void kernel_launch(void* const* d_in, const int* in_sizes, int n_in,
                              void* d_out, int out_size, void* d_ws, size_t ws_size,
                              hipStream_t stream) {
    const float* x  = (const float*)d_in[0];
    const float* wq = (const float*)d_in[1];
    const float* wk = (const float*)d_in[2];

    char* ws = (char*)d_ws;
    unsigned short* wqT = (unsigned short*)(ws);               //    524,288 B
    unsigned short* wkT = (unsigned short*)(ws + 524288);      //    524,288 B
    unsigned short* qb  = (unsigned short*)(ws + 1048576);     //  8,388,608 B
    unsigned short* kb  = (unsigned short*)(ws + 9437184);     //  8,388,608 B
    float*          tab = (float*)(ws + 17825792);             //     65,536 B

    float* out0 = (float*)d_out;
    float* aout = (float*)d_out + (size_t)B_ * S_ * D_;

    hipLaunchKernelGGL(k_transpose_w, dim3((2*H_*DK_*D_ + 255)/256), dim3(256), 0, stream,
                       wq, wk, wqT, wkT);
    hipLaunchKernelGGL(k_decay, dim3((H_*S_ + 255)/256), dim3(256), 0, stream, tab);
    hipLaunchKernelGGL(k_fill_all, dim3(116, 32), dim3(256), 0, stream, aout, out0);
    hipLaunchKernelGGL(k_proj, dim3(B_*S_/32, 2), dim3(256), 0, stream,
                       x, wqT, wkT, qb, kb);
    hipLaunchKernelGGL(k_score, dim3(512), dim3(256), 0, stream,
                       qb, kb, tab, aout);
}